// Round 8
// baseline (107.781 us; speedup 1.0000x reference)
//
#include <hip/hip_runtime.h>
#include <hip/hip_cooperative_groups.h>
#include <stdint.h>

namespace cg = cooperative_groups;

#define DIM 256
#define BATCH 16384
#define MARGIN 1.0f
#define EPSV 1e-6f

#define WPB 4                         // waves per block
#define PPW 8                         // pairs per wave (pipelined loop)
#define MAIN_BLOCKS (BATCH / (WPB * PPW))  // 512 blocks = 2/CU, all co-resident
#define STAGE_FLOATS (8 * DIM)        // 8 rows (pos h,hp,t,tp + neg h,hp,t,tp) = 8KB
#define WAVE_LDS (2 * STAGE_FLOATS)   // per-wave double buffer = 16KB

typedef float fx4 __attribute__((ext_vector_type(4)));

__device__ __forceinline__ float dot4(fx4 a, fx4 b) {
    return a.x * b.x + a.y * b.y + a.z * b.z + a.w * b.w;
}

// Async global->LDS, 16B/lane; LDS dest = wave-uniform base + lane*16 (HW rule).
__device__ __forceinline__ void gload_lds16(const void* g, void* l) {
    __builtin_amdgcn_global_load_lds(
        (const __attribute__((address_space(1))) uint32_t*)g,
        (__attribute__((address_space(3))) uint32_t*)l, 16, 0, 0);
}

// Counted vmem wait (T4): literal N keeps N newest ops in flight.
#define WAITV(n) asm volatile("s_waitcnt vmcnt(" #n ")" ::: "memory")

// Per-wave barrier-free gather pipeline (R7 structure) + cooperative grid-sync
// final reduction (this round's change: kills the 2nd-launch tail).
__global__ __launch_bounds__(256, 2) void transd_loss_kernel(
    const int* __restrict__ pos_x, const int* __restrict__ neg_x,
    const float* __restrict__ ent, const float* __restrict__ entm,
    const float* __restrict__ rel, const float* __restrict__ relm,
    float* __restrict__ partial, float* __restrict__ out) {
    __shared__ float rows[WPB * WAVE_LDS];  // 64 KB
    __shared__ float wsum[WPB];

    const int tid  = threadIdx.x;
    const int w    = tid >> 6;
    const int lane = tid & 63;
    const int lf   = lane * 4;                       // float offset, 16B/lane
    const int p0   = (blockIdx.x * WPB + w) * PPW;   // first pair of this wave
    float* wbuf = &rows[w * WAVE_LDS];

    int ph[2], pr[2], pt[2], nh[2], nr[2], nt[2];    // idx double-buffer
    fx4 rv[2][2], rpv[2][2];                         // rel rows [buf][side]

#define LOAD_IDX(b, j) do {                                              \
        const int p_ = p0 + (j);                                         \
        ph[b] = pos_x[p_ * 3 + 0];                                       \
        pr[b] = pos_x[p_ * 3 + 1];                                       \
        pt[b] = pos_x[p_ * 3 + 2];                                       \
        nh[b] = neg_x[p_ * 3 + 0];                                       \
        nr[b] = neg_x[p_ * 3 + 1];                                       \
        nt[b] = neg_x[p_ * 3 + 2];                                       \
    } while (0)

#define ISSUE_STAGE(b) do {                                              \
        float* sb_ = wbuf + (b) * STAGE_FLOATS;                          \
        const size_t hop = (size_t)ph[b] * DIM + lf;                     \
        const size_t top = (size_t)pt[b] * DIM + lf;                     \
        const size_t hon = (size_t)nh[b] * DIM + lf;                     \
        const size_t ton = (size_t)nt[b] * DIM + lf;                     \
        gload_lds16(ent  + hop, sb_ + 0 * DIM);                          \
        gload_lds16(entm + hop, sb_ + 1 * DIM);                          \
        gload_lds16(ent  + top, sb_ + 2 * DIM);                          \
        gload_lds16(entm + top, sb_ + 3 * DIM);                          \
        gload_lds16(ent  + hon, sb_ + 4 * DIM);                          \
        gload_lds16(entm + hon, sb_ + 5 * DIM);                          \
        gload_lds16(ent  + ton, sb_ + 6 * DIM);                          \
        gload_lds16(entm + ton, sb_ + 7 * DIM);                          \
        const size_t rop = (size_t)pr[b] * DIM + lf;                     \
        const size_t ron = (size_t)nr[b] * DIM + lf;                     \
        rv[b][0]  = *(const fx4*)(rel  + rop);                           \
        rpv[b][0] = *(const fx4*)(relm + rop);                           \
        rv[b][1]  = *(const fx4*)(rel  + ron);                           \
        rpv[b][1] = *(const fx4*)(relm + ron);                           \
    } while (0)

    // Prolog: idx0, idx1, stage0.
    LOAD_IDX(0, 0);
    LOAD_IDX(1, 1);
    ISSUE_STAGE(0);   // auto-wait vmcnt(6) for idx0; idx1 stays in flight

    float acc = 0.0f;
#pragma unroll
    for (int j = 0; j < PPW; ++j) {
        const int cb = j & 1;        // compute buffer
        const int nb = (j + 1) & 1;  // next-stage buffer
        if (j + 2 < PPW) LOAD_IDX(cb, j + 2);   // 6 ops (overwrites consumed idx)
        if (j + 1 < PPW) ISSUE_STAGE(nb);       // 12 ops (auto-wait hits oldest idx)

        // Counted wait: retire stage j, keep {idx(j+2), stage(j+1)} in flight.
        if (j <= PPW - 3)      { WAITV(18); }
        else if (j == PPW - 2) { WAITV(12); }
        else                   { WAITV(0);  }
        __builtin_amdgcn_sched_barrier(0);

        const float* sb = wbuf + cb * STAGE_FLOATS;
        fx4 h0  = *(const fx4*)(sb + 0 * DIM + lf);
        fx4 hp0 = *(const fx4*)(sb + 1 * DIM + lf);
        fx4 t0  = *(const fx4*)(sb + 2 * DIM + lf);
        fx4 tp0 = *(const fx4*)(sb + 3 * DIM + lf);
        fx4 h1  = *(const fx4*)(sb + 4 * DIM + lf);
        fx4 hp1 = *(const fx4*)(sb + 5 * DIM + lf);
        fx4 t1  = *(const fx4*)(sb + 6 * DIM + lf);
        fx4 tp1 = *(const fx4*)(sb + 7 * DIM + lf);

        float a0 = dot4(h0, hp0), b0 = dot4(t0, tp0);
        float a1 = dot4(h1, hp1), b1 = dot4(t1, tp1);
#pragma unroll
        for (int m = 32; m > 0; m >>= 1) {
            a0 += __shfl_xor(a0, m, 64);
            b0 += __shfl_xor(b0, m, 64);
            a1 += __shfl_xor(a1, m, 64);
            b1 += __shfl_xor(b1, m, 64);
        }
        const float ab0 = a0 - b0, ab1 = a1 - b1;

        fx4 d0 = rpv[cb][0] * ab0 + h0 + rv[cb][0] - t0 + EPSV;
        fx4 d1 = rpv[cb][1] * ab1 + h1 + rv[cb][1] - t1 + EPSV;
        float ss0 = dot4(d0, d0), ss1 = dot4(d1, d1);
#pragma unroll
        for (int m = 32; m > 0; m >>= 1) {
            ss0 += __shfl_xor(ss0, m, 64);
            ss1 += __shfl_xor(ss1, m, 64);
        }
        const float v = sqrtf(ss0) - sqrtf(ss1) + MARGIN;
        acc += v > 0.0f ? v : 0.0f;
    }
#undef LOAD_IDX
#undef ISSUE_STAGE

    if (lane == 0) wsum[w] = acc;
    __syncthreads();
    if (tid == 0)
        partial[blockIdx.x] = (wsum[0] + wsum[1]) + (wsum[2] + wsum[3]);

    // --- fused final reduction: grid sync, block 0 reduces 512 partials ---
    cg::this_grid().sync();
    if (blockIdx.x == 0) {
        float s = 0.0f;
        for (int i = tid; i < MAIN_BLOCKS; i += 256) s += partial[i];
#pragma unroll
        for (int m = 32; m > 0; m >>= 1) s += __shfl_xor(s, m, 64);
        __shared__ float smem[WPB];
        if (lane == 0) smem[w] = s;
        __syncthreads();
        if (tid == 0)
            out[0] = ((smem[0] + smem[1]) + (smem[2] + smem[3])) / (float)BATCH;
    }
}

extern "C" void kernel_launch(void* const* d_in, const int* in_sizes, int n_in,
                              void* d_out, int out_size, void* d_ws, size_t ws_size,
                              hipStream_t stream) {
    const int*   pos_x = (const int*)d_in[0];
    const int*   neg_x = (const int*)d_in[1];
    const float* ent   = (const float*)d_in[2];
    const float* entm  = (const float*)d_in[3];
    const float* rel   = (const float*)d_in[4];
    const float* relm  = (const float*)d_in[5];

    float* partial = (float*)d_ws;  // MAIN_BLOCKS floats = 2 KB
    float* out     = (float*)d_out;

    void* args[] = {(void*)&pos_x, (void*)&neg_x, (void*)&ent, (void*)&entm,
                    (void*)&rel, (void*)&relm, (void*)&partial, (void*)&out};
    hipLaunchCooperativeKernel((void*)transd_loss_kernel, dim3(MAIN_BLOCKS), dim3(256),
                               args, 0, stream);
}

// Round 9
// 34.774 us; speedup vs baseline: 3.0994x; 3.0994x over previous
//
#include <hip/hip_runtime.h>
#include <stdint.h>

#define DIM 256
#define BATCH 16384
#define MARGIN 1.0f
#define EPSV 1e-6f

#define WPB 4                         // waves per block
#define PPW 8                         // pairs per wave (pipelined loop)
#define MAIN_BLOCKS (BATCH / (WPB * PPW))  // 512 blocks = 2/CU, all resident
#define STAGE_FLOATS (8 * DIM)        // 8 rows (pos h,hp,t,tp + neg h,hp,t,tp) = 8KB
#define WAVE_LDS (2 * STAGE_FLOATS)   // per-wave double buffer = 16KB

typedef float fx4 __attribute__((ext_vector_type(4)));

__device__ __forceinline__ float dot4(fx4 a, fx4 b) {
    return a.x * b.x + a.y * b.y + a.z * b.z + a.w * b.w;
}

// Async global->LDS, 16B/lane; LDS dest = wave-uniform base + lane*16 (HW rule).
__device__ __forceinline__ void gload_lds16(const void* g, void* l) {
    __builtin_amdgcn_global_load_lds(
        (const __attribute__((address_space(1))) uint32_t*)g,
        (__attribute__((address_space(3))) uint32_t*)l, 16, 0, 0);
}

// Counted vmem wait (T4): literal N keeps N newest ops in flight.
#define WAITV(n) asm volatile("s_waitcnt vmcnt(" #n ")" ::: "memory")

// Per-wave barrier-free pipeline over 8 pairs. vmem ops per region:
//   LOAD_IDX = 6 (dword), ISSUE_STAGE = 8 DMA + 4 rel vec = 12.
// Issue order per iter j: LOAD_IDX(j+2) [6] -> ISSUE_STAGE(j+1) [12]
// (auto-wait for idx(j+1) regs hits the OLDEST ops -> vmcnt(18), pipe intact)
// -> manual WAITV(18) -> stage j retired -> compute pair j.
__global__ __launch_bounds__(256, 2) void transd_loss_kernel(
    const int* __restrict__ pos_x, const int* __restrict__ neg_x,
    const float* __restrict__ ent, const float* __restrict__ entm,
    const float* __restrict__ rel, const float* __restrict__ relm,
    float* __restrict__ partial) {
    __shared__ float rows[WPB * WAVE_LDS];  // 64 KB
    __shared__ float wsum[WPB];

    const int tid  = threadIdx.x;
    const int w    = tid >> 6;
    const int lane = tid & 63;
    const int lf   = lane * 4;                       // float offset, 16B/lane
    const int p0   = (blockIdx.x * WPB + w) * PPW;   // first pair of this wave
    float* wbuf = &rows[w * WAVE_LDS];

    int ph[2], pr[2], pt[2], nh[2], nr[2], nt[2];    // idx double-buffer
    fx4 rv[2][2], rpv[2][2];                         // rel rows [buf][side]

#define LOAD_IDX(b, j) do {                                              \
        const int p_ = p0 + (j);                                         \
        ph[b] = pos_x[p_ * 3 + 0];                                       \
        pr[b] = pos_x[p_ * 3 + 1];                                       \
        pt[b] = pos_x[p_ * 3 + 2];                                       \
        nh[b] = neg_x[p_ * 3 + 0];                                       \
        nr[b] = neg_x[p_ * 3 + 1];                                       \
        nt[b] = neg_x[p_ * 3 + 2];                                       \
    } while (0)

#define ISSUE_STAGE(b) do {                                              \
        float* sb_ = wbuf + (b) * STAGE_FLOATS;                          \
        const size_t hop = (size_t)ph[b] * DIM + lf;                     \
        const size_t top = (size_t)pt[b] * DIM + lf;                     \
        const size_t hon = (size_t)nh[b] * DIM + lf;                     \
        const size_t ton = (size_t)nt[b] * DIM + lf;                     \
        gload_lds16(ent  + hop, sb_ + 0 * DIM);                          \
        gload_lds16(entm + hop, sb_ + 1 * DIM);                          \
        gload_lds16(ent  + top, sb_ + 2 * DIM);                          \
        gload_lds16(entm + top, sb_ + 3 * DIM);                          \
        gload_lds16(ent  + hon, sb_ + 4 * DIM);                          \
        gload_lds16(entm + hon, sb_ + 5 * DIM);                          \
        gload_lds16(ent  + ton, sb_ + 6 * DIM);                          \
        gload_lds16(entm + ton, sb_ + 7 * DIM);                          \
        const size_t rop = (size_t)pr[b] * DIM + lf;                     \
        const size_t ron = (size_t)nr[b] * DIM + lf;                     \
        rv[b][0]  = *(const fx4*)(rel  + rop);                           \
        rpv[b][0] = *(const fx4*)(relm + rop);                           \
        rv[b][1]  = *(const fx4*)(rel  + ron);                           \
        rpv[b][1] = *(const fx4*)(relm + ron);                           \
    } while (0)

    // Prolog: idx0, idx1, stage0.
    LOAD_IDX(0, 0);
    LOAD_IDX(1, 1);
    ISSUE_STAGE(0);   // auto-wait vmcnt(6) for idx0; idx1 stays in flight

    float acc = 0.0f;
#pragma unroll
    for (int j = 0; j < PPW; ++j) {
        const int cb = j & 1;        // compute buffer
        const int nb = (j + 1) & 1;  // next-stage buffer
        if (j + 2 < PPW) LOAD_IDX(cb, j + 2);   // 6 ops (overwrites consumed idx)
        if (j + 1 < PPW) ISSUE_STAGE(nb);       // 12 ops (auto-wait hits oldest idx)

        // Counted wait: retire stage j, keep {idx(j+2), stage(j+1)} in flight.
        if (j <= PPW - 3)      { WAITV(18); }
        else if (j == PPW - 2) { WAITV(12); }
        else                   { WAITV(0);  }
        __builtin_amdgcn_sched_barrier(0);

        const float* sb = wbuf + cb * STAGE_FLOATS;
        fx4 h0  = *(const fx4*)(sb + 0 * DIM + lf);
        fx4 hp0 = *(const fx4*)(sb + 1 * DIM + lf);
        fx4 t0  = *(const fx4*)(sb + 2 * DIM + lf);
        fx4 tp0 = *(const fx4*)(sb + 3 * DIM + lf);
        fx4 h1  = *(const fx4*)(sb + 4 * DIM + lf);
        fx4 hp1 = *(const fx4*)(sb + 5 * DIM + lf);
        fx4 t1  = *(const fx4*)(sb + 6 * DIM + lf);
        fx4 tp1 = *(const fx4*)(sb + 7 * DIM + lf);

        float a0 = dot4(h0, hp0), b0 = dot4(t0, tp0);
        float a1 = dot4(h1, hp1), b1 = dot4(t1, tp1);
#pragma unroll
        for (int m = 32; m > 0; m >>= 1) {
            a0 += __shfl_xor(a0, m, 64);
            b0 += __shfl_xor(b0, m, 64);
            a1 += __shfl_xor(a1, m, 64);
            b1 += __shfl_xor(b1, m, 64);
        }
        const float ab0 = a0 - b0, ab1 = a1 - b1;

        fx4 d0 = rpv[cb][0] * ab0 + h0 + rv[cb][0] - t0 + EPSV;
        fx4 d1 = rpv[cb][1] * ab1 + h1 + rv[cb][1] - t1 + EPSV;
        float ss0 = dot4(d0, d0), ss1 = dot4(d1, d1);
#pragma unroll
        for (int m = 32; m > 0; m >>= 1) {
            ss0 += __shfl_xor(ss0, m, 64);
            ss1 += __shfl_xor(ss1, m, 64);
        }
        const float v = sqrtf(ss0) - sqrtf(ss1) + MARGIN;
        acc += v > 0.0f ? v : 0.0f;
    }
#undef LOAD_IDX
#undef ISSUE_STAGE

    if (lane == 0) wsum[w] = acc;
    __syncthreads();
    if (tid == 0)
        partial[blockIdx.x] = (wsum[0] + wsum[1]) + (wsum[2] + wsum[3]);
}

// Deterministic single-block reduction of MAIN_BLOCKS floats -> out[0] = sum/BATCH.
__global__ __launch_bounds__(256) void reduce_kernel(const float* __restrict__ partial,
                                                     float* __restrict__ out) {
    const int lane = threadIdx.x & 63;
    float s = 0.0f;
    for (int i = threadIdx.x; i < MAIN_BLOCKS; i += 256) s += partial[i];
#pragma unroll
    for (int m = 32; m > 0; m >>= 1) s += __shfl_xor(s, m, 64);
    __shared__ float smem[4];
    if (lane == 0) smem[threadIdx.x >> 6] = s;
    __syncthreads();
    if (threadIdx.x == 0)
        out[0] = ((smem[0] + smem[1]) + (smem[2] + smem[3])) / (float)BATCH;
}

extern "C" void kernel_launch(void* const* d_in, const int* in_sizes, int n_in,
                              void* d_out, int out_size, void* d_ws, size_t ws_size,
                              hipStream_t stream) {
    const int*   pos_x = (const int*)d_in[0];
    const int*   neg_x = (const int*)d_in[1];
    const float* ent   = (const float*)d_in[2];
    const float* entm  = (const float*)d_in[3];
    const float* rel   = (const float*)d_in[4];
    const float* relm  = (const float*)d_in[5];

    float* partial = (float*)d_ws;  // MAIN_BLOCKS floats = 2 KB
    float* out     = (float*)d_out;

    transd_loss_kernel<<<MAIN_BLOCKS, 256, 0, stream>>>(pos_x, neg_x, ent, entm, rel, relm, partial);
    reduce_kernel<<<1, 256, 0, stream>>>(partial, out);
}